// Round 2
// baseline (94.335 us; speedup 1.0000x reference)
//
#include <hip/hip_runtime.h>
#include <stdint.h>

// SCLinear: out = sc_mat_mac_p(x, W, b, lut, 32)  (forward value of
// lin + stop_grad(p - lin) is exactly p).
// lut[i][j] == floor(i*j/32)  =>  sgn*lut[|a|,|b|] == trunc-toward-zero(a*b/32).
// Exact small-integer arithmetic; no lut memory needed.
//
// R15: SINGLE DISPATCH, REDUNDANT GLOBAL MAX.
// Post-mortem of R13/R14: non-fill time was 34.1us (1 dispatch, 18us
// intra-kernel handshake) vs 36.6us (2 dispatches, no handshake). The
// only consistent decomposition is per-dispatch overhead ~10-12us with
// the kernels themselves at roofline (~12us combined). So the lever is
// DISPATCH COUNT. This version: ONE kernel, no inter-block communication
// at all -- every block recomputes the exact global amax/dmax itself.
//   grid 256 blocks x 512 threads, 2 x-rows per block:
//   phase 1: cooperative strided scan of x (512KB) + W (256KB) + b ->
//            exact (e2,e1). Aggregate 197MB of L2-resident reads ~5.7us
//            at 34.5 TB/s; also warms W for phase 3.
//   phase 2: quantize the block's 2 rows into LDS (int8 packed).
//   phase 3: thread (r,o)=(tid>>8, tid&255) integer-MACs W row o against
//            row r. Same exact math as the verified R8-R14 kernels.
// No workspace, no speculation, no fixup path.

#define MROWS 512
#define KDIM  256
#define OCOLS 256
#define NTHR  512
#define RPB   2                 // rows per block
#define NBLK  (MROWS / RPB)     // 256

__device__ __forceinline__ void get_scales(float amax, float dmax, int& e2, int& e1) {
    if (amax == 0.0f) amax = 1.0f;
    if (dmax == 0.0f) dmax = 1.0f;
    float q2 = 32.0f / amax;
    float q1 = 32.0f / dmax;
    int f2 = (q2 >= 1073741824.0f) ? 0x40000000 : (int)floorf(q2);
    int f1 = (q1 >= 1073741824.0f) ? 0x40000000 : (int)floorf(q1);
    if (f2 < 1) f2 = 1;
    if (f1 < 1) f1 = 1;
    e2 = 31 - __clz(f2);
    e1 = 31 - __clz(f1);
}

__device__ __forceinline__ float max4(float4 v) {
    return fmaxf(fmaxf(fabsf(v.x), fabsf(v.y)), fmaxf(fabsf(v.z), fabsf(v.w)));
}

__global__ __launch_bounds__(NTHR)
void k_fused(const float* __restrict__ x, const float* __restrict__ W,
             const float* __restrict__ b, float* __restrict__ out) {
    __shared__ unsigned int a_sh[RPB][KDIM / 4];
    __shared__ float sm[2 * (NTHR / 64)];
    __shared__ int s_e[2];

    const int tid  = threadIdx.x;
    const int wave = tid >> 6;
    const int m0   = blockIdx.x * RPB;

    // ---- phase 1: redundant exact global abs-max over x, W, b ----
    const float4* xf = (const float4*)x;     // 32768 float4
    const float4* wf = (const float4*)W;     // 16384 float4
    float va = 0.0f, vd = 0.0f;
    #pragma unroll 8
    for (int i = 0; i < 32768 / NTHR; ++i)   // 64 per thread
        va = fmaxf(va, max4(xf[i * NTHR + tid]));
    #pragma unroll 8
    for (int i = 0; i < 16384 / NTHR; ++i)   // 32 per thread
        vd = fmaxf(vd, max4(wf[i * NTHR + tid]));
    if (tid < 64)                            // b: 64 float4
        vd = fmaxf(vd, max4(((const float4*)b)[tid]));
    #pragma unroll
    for (int s = 32; s >= 1; s >>= 1) {
        va = fmaxf(va, __shfl_xor(va, s, 64));
        vd = fmaxf(vd, __shfl_xor(vd, s, 64));
    }
    if ((tid & 63) == 0) { sm[2 * wave] = va; sm[2 * wave + 1] = vd; }
    __syncthreads();
    if (tid == 0) {
        float a = sm[0], d = sm[1];
        #pragma unroll
        for (int i = 1; i < NTHR / 64; ++i) {
            a = fmaxf(a, sm[2 * i]);
            d = fmaxf(d, sm[2 * i + 1]);
        }
        int e2, e1;
        get_scales(a, d, e2, e1);
        s_e[0] = e2; s_e[1] = e1;
    }
    __syncthreads();

    const int e2 = s_e[0];
    const int e1 = s_e[1];
    const float sn2f = (float)(1 << e2);
    const float sn1f = (float)(1 << e1);

    // ---- phase 2: quantize the block's RPB x-rows into LDS (packed int8) ----
    if (tid < RPB * (KDIM / 4)) {            // 128 threads
        const int r = tid >> 6;
        const int o = tid & 63;
        float4 xv = xf[(size_t)(m0 + r) * (KDIM / 4) + o];
        int a0 = (int)(xv.x * sn2f) & 0xFF;
        int a1 = (int)(xv.y * sn2f) & 0xFF;
        int a2 = (int)(xv.z * sn2f) & 0xFF;
        int a3 = (int)(xv.w * sn2f) & 0xFF;
        a_sh[r][o] = (unsigned int)(a0 | (a1 << 8) | (a2 << 16) | (a3 << 24));
    }
    __syncthreads();

    // ---- phase 3: integer MAC, thread (r,o) -> out[m0+r][o] ----
    const int o = tid & (OCOLS - 1);
    const int r = tid >> 8;                  // 0 or 1
    const float4* wrow = (const float4*)(W + (size_t)o * KDIM);
    const unsigned int* arow = a_sh[r];
    int sum = 0;
    #pragma unroll 8
    for (int kk = 0; kk < KDIM / 4; ++kk) {
        float4 wv = wrow[kk];
        unsigned int ap = arow[kk];
        float wfv[4] = {wv.x, wv.y, wv.z, wv.w};
        #pragma unroll
        for (int j = 0; j < 4; ++j) {
            int bv = (int)(wfv[j] * sn1f);
            int av = ((int)(ap << (24 - 8 * j))) >> 24;   // sign-extended byte j
            int s  = av * bv;
            sum += (s + ((s >> 31) & 31)) >> 5;           // == sgn*lut[|av|,|bv|]
        }
    }

    const int cc = (int)(b[o] * sn1f);
    const int d  = ((sum + ((sum >> 31) & ((1 << e2) - 1))) >> e2) + cc;
    out[(size_t)(m0 + r) * OCOLS + o] = (float)d * (1.0f / sn1f);
}

extern "C" void kernel_launch(void* const* d_in, const int* in_sizes, int n_in,
                              void* d_out, int out_size, void* d_ws, size_t ws_size,
                              hipStream_t stream) {
    const float* x = (const float*)d_in[0];
    const float* W = (const float*)d_in[1];
    const float* b = (const float*)d_in[2];
    // d_in[3] (lut) unused: lut[i][j] == floor(i*j/32), computed in-ALU.
    float* out = (float*)d_out;
    (void)d_ws; (void)ws_size;               // no workspace needed

    k_fused<<<NBLK, NTHR, 0, stream>>>(x, W, b, out);
}

// Round 9
// 87.766 us; speedup vs baseline: 1.0749x; 1.0749x over previous
//
#include <hip/hip_runtime.h>
#include <stdint.h>

// SCLinear: out = sc_mat_mac_p(x, W, b, lut, 32)  (forward value of
// lin + stop_grad(p - lin) is exactly p).
// lut[i][j] == floor(i*j/32)  =>  sgn*lut[|a|,|b|] == trunc-toward-zero(a*b/32).
// Exact small-integer arithmetic; no lut memory needed.
//
// R22 == R16 resubmitted verbatim (R16-R21 all died in broker
// infrastructure, kernel never ran).
//
// R16: R15 + STAGGERED SCAN (anti slice-camping).
// R15 post-mortem: redundant global-max scan took ~36us (not the ~6us the
// 34.5 TB/s L2 aggregate predicts) because all 256 blocks walk the SAME
// address stream in lockstep -> at any instant the 32 blocks of an XCD
// hit the same L2 slice/line (slice camping), defeating slice-level
// parallelism (HBM 1%, VALUBusy 24%, stalls 76%). Fix: rotate each
// block's scan start: block B reads x from float4 index B*128 (mod 32768)
// and W from B*64 (mod 16384). Max is order-invariant -> identical
// scales; every instant now touches 256 distinct lines spread over all
// slices/channels. Everything else identical to R15 (single dispatch,
// no workspace, no poll, no fixup).

#define MROWS 512
#define KDIM  256
#define OCOLS 256
#define NTHR  512
#define RPB   2                 // rows per block
#define NBLK  (MROWS / RPB)     // 256

__device__ __forceinline__ void get_scales(float amax, float dmax, int& e2, int& e1) {
    if (amax == 0.0f) amax = 1.0f;
    if (dmax == 0.0f) dmax = 1.0f;
    float q2 = 32.0f / amax;
    float q1 = 32.0f / dmax;
    int f2 = (q2 >= 1073741824.0f) ? 0x40000000 : (int)floorf(q2);
    int f1 = (q1 >= 1073741824.0f) ? 0x40000000 : (int)floorf(q1);
    if (f2 < 1) f2 = 1;
    if (f1 < 1) f1 = 1;
    e2 = 31 - __clz(f2);
    e1 = 31 - __clz(f1);
}

__device__ __forceinline__ float max4(float4 v) {
    return fmaxf(fmaxf(fabsf(v.x), fabsf(v.y)), fmaxf(fabsf(v.z), fabsf(v.w)));
}

__global__ __launch_bounds__(NTHR)
void k_fused(const float* __restrict__ x, const float* __restrict__ W,
             const float* __restrict__ b, float* __restrict__ out) {
    __shared__ unsigned int a_sh[RPB][KDIM / 4];
    __shared__ float sm[2 * (NTHR / 64)];
    __shared__ int s_e[2];

    const int tid  = threadIdx.x;
    const int wave = tid >> 6;
    const int m0   = blockIdx.x * RPB;

    // ---- phase 1: redundant exact global abs-max over x, W, b ----
    // Staggered start per block so concurrent blocks hit different L2
    // slices / HBM channels (max is order-invariant -> same result).
    const float4* xf = (const float4*)x;     // 32768 float4
    const float4* wf = (const float4*)W;     // 16384 float4
    const unsigned rotx = (unsigned)blockIdx.x * 128u;
    const unsigned rotw = (unsigned)blockIdx.x * 64u;
    float va = 0.0f, vd = 0.0f;
    {
        unsigned base = ((unsigned)tid + rotx);
        #pragma unroll 8
        for (int i = 0; i < 32768 / NTHR; ++i) {         // 64 per thread
            unsigned idx = (base + (unsigned)(i * NTHR)) & 32767u;
            va = fmaxf(va, max4(xf[idx]));
        }
    }
    {
        unsigned base = ((unsigned)tid + rotw);
        #pragma unroll 8
        for (int i = 0; i < 16384 / NTHR; ++i) {         // 32 per thread
            unsigned idx = (base + (unsigned)(i * NTHR)) & 16383u;
            vd = fmaxf(vd, max4(wf[idx]));
        }
    }
    if (tid < 64)                            // b: 64 float4
        vd = fmaxf(vd, max4(((const float4*)b)[tid]));
    #pragma unroll
    for (int s = 32; s >= 1; s >>= 1) {
        va = fmaxf(va, __shfl_xor(va, s, 64));
        vd = fmaxf(vd, __shfl_xor(vd, s, 64));
    }
    if ((tid & 63) == 0) { sm[2 * wave] = va; sm[2 * wave + 1] = vd; }
    __syncthreads();
    if (tid == 0) {
        float a = sm[0], d = sm[1];
        #pragma unroll
        for (int i = 1; i < NTHR / 64; ++i) {
            a = fmaxf(a, sm[2 * i]);
            d = fmaxf(d, sm[2 * i + 1]);
        }
        int e2, e1;
        get_scales(a, d, e2, e1);
        s_e[0] = e2; s_e[1] = e1;
    }
    __syncthreads();

    const int e2 = s_e[0];
    const int e1 = s_e[1];
    const float sn2f = (float)(1 << e2);
    const float sn1f = (float)(1 << e1);

    // ---- phase 2: quantize the block's RPB x-rows into LDS (packed int8) ----
    if (tid < RPB * (KDIM / 4)) {            // 128 threads
        const int r = tid >> 6;
        const int o = tid & 63;
        float4 xv = xf[(size_t)(m0 + r) * (KDIM / 4) + o];
        int a0 = (int)(xv.x * sn2f) & 0xFF;
        int a1 = (int)(xv.y * sn2f) & 0xFF;
        int a2 = (int)(xv.z * sn2f) & 0xFF;
        int a3 = (int)(xv.w * sn2f) & 0xFF;
        a_sh[r][o] = (unsigned int)(a0 | (a1 << 8) | (a2 << 16) | (a3 << 24));
    }
    __syncthreads();

    // ---- phase 3: integer MAC, thread (r,o) -> out[m0+r][o] ----
    const int o = tid & (OCOLS - 1);
    const int r = tid >> 8;                  // 0 or 1
    const float4* wrow = (const float4*)(W + (size_t)o * KDIM);
    const unsigned int* arow = a_sh[r];
    int sum = 0;
    #pragma unroll 8
    for (int kk = 0; kk < KDIM / 4; ++kk) {
        float4 wv = wrow[kk];
        unsigned int ap = arow[kk];
        float wfv[4] = {wv.x, wv.y, wv.z, wv.w};
        #pragma unroll
        for (int j = 0; j < 4; ++j) {
            int bv = (int)(wfv[j] * sn1f);
            int av = ((int)(ap << (24 - 8 * j))) >> 24;   // sign-extended byte j
            int s  = av * bv;
            sum += (s + ((s >> 31) & 31)) >> 5;           // == sgn*lut[|av|,|bv|]
        }
    }

    const int cc = (int)(b[o] * sn1f);
    const int d  = ((sum + ((sum >> 31) & ((1 << e2) - 1))) >> e2) + cc;
    out[(size_t)(m0 + r) * OCOLS + o] = (float)d * (1.0f / sn1f);
}

extern "C" void kernel_launch(void* const* d_in, const int* in_sizes, int n_in,
                              void* d_out, int out_size, void* d_ws, size_t ws_size,
                              hipStream_t stream) {
    const float* x = (const float*)d_in[0];
    const float* W = (const float*)d_in[1];
    const float* b = (const float*)d_in[2];
    // d_in[3] (lut) unused: lut[i][j] == floor(i*j/32), computed in-ALU.
    float* out = (float*)d_out;
    (void)d_ws; (void)ws_size;               // no workspace needed

    k_fused<<<NBLK, NTHR, 0, stream>>>(x, W, b, out);
}